// Round 12
// baseline (80.860 us; speedup 1.0000x reference)
//
#include <hip/hip_runtime.h>
#include <math.h>

#define NB   16      // batch
#define NM   4096    // preds per image
#define NT   512     // targets per image
#define CAP  16      // max candidates per row (overflow -> exact fallback)
#define IOU_THR 0.1f
#define EPSG 1e-7f
#define NROWS (NB*NM)
#define T_WIN 512            // threads per auction block
#define NWIN  (NM / T_WIN)   // 8 ascending windows, 1 row/thread/window
#define SUBP  8              // chaotic sub-passes per barrier round
#define SENT  0xFFFFFFFFu

// ---------------------------------------------------------------------------
// Kernel 1: wave-per-row candidate build, targets staged in LDS per 64-row
// block. Ballot compaction, ascending-j order, transposed (e-major) storage
// so kernel-2's per-window register prefetch is coalesced.  (R8, measured.)
// ---------------------------------------------------------------------------
__global__ __launch_bounds__(256) void cand_kernel(
    const float4* __restrict__ pred, const float4* __restrict__ tgt,
    int* __restrict__ counts, float2* __restrict__ cands)
{
    __shared__ float4 t_lds[NT];
    const int rb = blockIdx.x * 64;          // 64 rows per block, same image
    const int b  = rb >> 12;                 // NM = 4096
    for (int i = threadIdx.x; i < NT; i += 256)
        t_lds[i] = tgt[b * NT + i];
    __syncthreads();

    const int wv = threadIdx.x >> 6, lane = threadIdx.x & 63;
    for (int rr = 0; rr < 16; ++rr) {
        const int row = rb + wv * 16 + rr;
        float4 p = pred[row];                // wave-uniform load
        float area_p = (p.z - p.x) * (p.w - p.y);
        int base = 0;
        #pragma unroll
        for (int pass = 0; pass < NT / 64; ++pass) {
            int j = (pass << 6) + lane;
            float4 t = t_lds[j];
            float area_t = (t.z - t.x) * (t.w - t.y);
            float w = fmaxf(fminf(p.z, t.z) - fmaxf(p.x, t.x), 0.f);
            float h = fmaxf(fminf(p.w, t.w) - fmaxf(p.y, t.y), 0.f);
            float inter = w * h;
            float uni   = (area_p + area_t) - inter;   // ref association
            float iou   = inter / uni;
            bool q = iou > IOU_THR;
            unsigned long long m = __ballot(q);
            if (q) {
                int off = base + __popcll(m & ((1ull << lane) - 1ull));
                if (off < CAP)
                    cands[(size_t)off * NROWS + row] = make_float2(iou, __int_as_float(j));
            }
            base += __popcll(m);
        }
        if (lane == 0) counts[row] = base;   // > CAP flags overflow
    }
}

// ---------------------------------------------------------------------------
// Kernel 2: windowed auction, 512 threads/image, 1 row per thread per window.
// Ascending windows resolved to their internal fixed point are FINAL (claim
// influence flows strictly upward in row index). Each barrier round runs
// SUBP chaotic sub-passes {recheck -> rescan -> atomicMin settle} so snipe
// chains propagate multiple hops per round; the monotone lastprop stamp at
// the barrier certifies the fixed point (a full round with zero proposals).
// All cross-wave correctness flows through barriers only (R11 lesson).
// claim[j] = min proposer (monotone) -> unique fixed point == serial greedy.
// ---------------------------------------------------------------------------
__global__ __launch_bounds__(T_WIN) void win_auction(
    const float4* __restrict__ pred, const float4* __restrict__ tgt,
    const int* __restrict__ counts, const float2* __restrict__ cands,
    float* __restrict__ per_img)
{
    __shared__ float4   t_lds[NT];       // 8 KB
    __shared__ unsigned claim[NT];       // 2 KB
    __shared__ int lastprop;             // monotone round stamp
    __shared__ unsigned char winovf[NWIN];
    __shared__ int ovf_min, ovf_res;
    __shared__ float rvv[T_WIN / 64];  __shared__ int rjj[T_WIN / 64];
    __shared__ float rls[T_WIN / 64];  __shared__ float rcs[T_WIN / 64];

    const int b = blockIdx.x, t = threadIdx.x, gbase = b * NM;
    const int wv = t >> 6, lane = t & 63;

    t_lds[t] = tgt[b * NT + t];
    claim[t] = SENT;
    if (t < NWIN) winovf[t] = 0;
    if (t == 0) lastprop = -1;
    __syncthreads();

    // all counts up front (8 coalesced loads), flag overflow windows
    int allCnt[NWIN];
    #pragma unroll
    for (int k = 0; k < NWIN; ++k) {
        allCnt[k] = counts[gbase + k * T_WIN + t];
        if (allCnt[k] > CAP) winovf[k] = 1;
    }
    // prefetch window 0 candidates into registers
    float2 nC[CAP];
    #pragma unroll
    for (int e = 0; e < CAP; ++e) nC[e] = cands[(size_t)e * NROWS + gbase + t];
    __syncthreads();                      // winovf visible to all

    int rglob = 0;
    float2 cC[CAP];
    for (int w = 0; w < NWIN; ++w) {
        #pragma unroll
        for (int e = 0; e < CAP; ++e) cC[e] = nC[e];
        const int cCnt = allCnt[w];
        if (w + 1 < NWIN) {               // prefetch next window; hides under rounds
            #pragma unroll
            for (int e = 0; e < CAP; ++e)
                nC[e] = cands[(size_t)e * NROWS + gbase + (w + 1) * T_WIN + t];
        }
        const unsigned row = (unsigned)(w * T_WIN + t);
        int  stt  = (cCnt > 0 && cCnt <= CAP) ? 0 : 2;   // 0=UNRES 1=HOLD 2=DONE
        int  myj  = -1;
        bool isovf = (cCnt > CAP);
        int  ovfj  = -1;

        for (;;) {
            // ---- auction rounds to window fixed point (1 barrier/round) ----
            for (;;) {
                bool did = false;
                #pragma unroll 1
                for (int s = 0; s < SUBP; ++s) {
                    if (stt == 1 && claim[myj] != row) stt = 0;  // sniped: rejoin
                    if (stt == 0) {
                        for (int it = 0; it <= CAP; ++it) {      // bounded retry
                            float bv = -1.f; int bj = -1;
                            #pragma unroll
                            for (int e = 0; e < CAP; ++e) {      // independent reads
                                float2 ce = cC[e];
                                int j = __float_as_int(ce.y) & (NT - 1);
                                unsigned cj = claim[j];
                                if (e < cCnt && cj >= row && ce.x > bv) { bv = ce.x; bj = j; }
                            }
                            if (bj < 0) { stt = 2; break; }      // invalid (permanent)
                            did = true;
                            unsigned old = atomicMin(&claim[bj], row);
                            if (old >= row) { myj = bj; stt = 1; break; }   // settled
                            // lost: claim[bj] < row is permanent -> excluded next scan
                        }
                    }
                }
                if (did) lastprop = rglob;    // benign: all writers store same value
                __syncthreads();
                int lp = lastprop;
                ++rglob;
                if (lp < rglob - 1) break;    // zero-proposal round: fixed point
            }
            // ---- overflow fallback (count > CAP, ~never) ----
            if (!winovf[w]) break;
            if (t == 0) ovf_min = 0x7FFFFFFF;
            __syncthreads();
            bool pend = isovf && (ovfj < 0 || claim[ovfj] != row);
            if (pend) atomicMin(&ovf_min, (int)row);
            __syncthreads();
            const int rowF = ovf_min;                            // uniform
            if (rowF == 0x7FFFFFFF) break;                       // window done
            {   // exact claim-aware argmax over all 512 targets (thread t = target t)
                float4 p4 = pred[gbase + rowF];                  // uniform address
                float4 tt = t_lds[t];
                float area_p = (p4.z - p4.x) * (p4.w - p4.y);
                float area_t = (tt.z - tt.x) * (tt.w - tt.y);
                float wd = fmaxf(fminf(p4.z, tt.z) - fmaxf(p4.x, tt.x), 0.f);
                float hd = fmaxf(fminf(p4.w, tt.w) - fmaxf(p4.y, tt.y), 0.f);
                float inter = wd * hd;
                float iou = inter / ((area_p + area_t) - inter);
                bool freej = claim[t] > (unsigned)rowF;          // smaller = final-used
                float v = freej ? iou : -1.f;
                int bj = freej ? t : NT;
                #pragma unroll
                for (int off = 1; off < 64; off <<= 1) {
                    float ov = __shfl_xor(v, off);
                    int   oj = __shfl_xor(bj, off);
                    if (ov > v || (ov == v && oj < bj)) { v = ov; bj = oj; }
                }
                if (lane == 0) { rvv[wv] = v; rjj[wv] = bj; }
            }
            __syncthreads();
            if (t == 0) {
                float v = rvv[0]; int bj = rjj[0];
                for (int q = 1; q < T_WIN / 64; ++q)
                    if (rvv[q] > v || (rvv[q] == v && rjj[q] < bj)) { v = rvv[q]; bj = rjj[q]; }
                if (v > IOU_THR) { ovf_res = bj; claim[bj] = (unsigned)rowF; }  // steal
                else ovf_res = -1;
            }
            __syncthreads();
            if ((int)row == rowF) {
                if (ovf_res >= 0) ovfj = ovf_res;   // matched (recorded in claim)
                else isovf = false;                 // permanently invalid
            }
            // displaced holder (if any) re-detected at next round's recheck
        }
    }
    __syncthreads();

    // ---- commit by target: claim[j]==r <=> r matched j (unique fixed point) ----
    float ls = 0.f, cs = 0.f;
    {
        unsigned r = claim[t];
        if (r != SENT) {
            float4 p4 = pred[gbase + (int)r];
            float4 tt = t_lds[t];
            float inter = fmaxf(fminf(p4.z, tt.z) - fmaxf(p4.x, tt.x), 0.f) *
                          fmaxf(fminf(p4.w, tt.w) - fmaxf(p4.y, tt.y), 0.f);
            float area_p = (p4.z - p4.x) * (p4.w - p4.y);
            float area_t = (tt.z - tt.x) * (tt.w - tt.y);
            float uni = area_p + area_t - inter;
            float iou = inter / (uni + EPSG);
            float enc = (fmaxf(p4.z, tt.z) - fminf(p4.x, tt.x)) *
                        (fmaxf(p4.w, tt.w) - fminf(p4.y, tt.y));
            float giou = iou - (enc - uni) / (enc + EPSG);
            ls = 1.f - giou;
            cs = 1.f;
        }
    }
    #pragma unroll
    for (int off = 32; off >= 1; off >>= 1) {
        ls += __shfl_xor(ls, off);
        cs += __shfl_xor(cs, off);
    }
    if (lane == 0) { rls[wv] = ls; rcs[wv] = cs; }
    __syncthreads();
    if (t == 0) {
        float L = 0.f, C = 0.f;
        for (int q = 0; q < T_WIN / 64; ++q) { L += rls[q]; C += rcs[q]; }
        per_img[b] = (C > 0.f) ? L / C : 0.f;
    }
}

// ---------------------------------------------------------------------------
// Kernel 3: mean over images -> scalar output. Deterministic (no atomics).
// ---------------------------------------------------------------------------
__global__ void reduce_kernel(const float* __restrict__ per_img,
                              float* __restrict__ out)
{
    if (threadIdx.x == 0 && blockIdx.x == 0) {
        float s = 0.f;
        for (int i = 0; i < NB; ++i) s += per_img[i];
        out[0] = s / (float)NB;
    }
}

extern "C" void kernel_launch(void* const* d_in, const int* in_sizes, int n_in,
                              void* d_out, int out_size, void* d_ws, size_t ws_size,
                              hipStream_t stream)
{
    const float4* pred = (const float4*)d_in[0];   // [16,4096,4] f32
    const float4* tgt  = (const float4*)d_in[1];   // [16,512,4]  f32

    char* ws = (char*)d_ws;
    // layout: counts [NROWS] i32 | cands [CAP*NROWS] float2 | per_img [NB] f32
    int*    counts  = (int*)ws;
    size_t  off1    = (size_t)NROWS * sizeof(int);                 // 256 KB
    float2* cands   = (float2*)(ws + off1);
    size_t  off2    = off1 + (size_t)CAP * NROWS * sizeof(float2); // +8 MB
    float*  per_img = (float*)(ws + off2);

    cand_kernel<<<NROWS / 64, 256, 0, stream>>>(pred, tgt, counts, cands);
    win_auction<<<NB, T_WIN, 0, stream>>>(pred, tgt, counts, cands, per_img);
    reduce_kernel<<<1, 64, 0, stream>>>(per_img, (float*)d_out);
}

// Round 13
// 64.300 us; speedup vs baseline: 1.2575x; 1.2575x over previous
//
#include <hip/hip_runtime.h>
#include <math.h>

#define NB   16      // batch
#define NM   4096    // preds per image
#define NT   512     // targets per image
#define CAP  16      // max candidates per row (overflow -> exact fallback)
#define IOU_THR 0.1f
#define EPSG 1e-7f
#define NROWS (NB*NM)
#define T_WIN 1024           // threads per auction block (R13: was 512)
#define NWIN  (NM / T_WIN)   // 4 ascending windows, 1 row/thread/window
#define SENT  0xFFFFFFFFu

// ---------------------------------------------------------------------------
// Kernel 1: wave-per-row candidate build, v2: pred loads software-pipelined
// (kills serial L2 stalls) and 2 rows per pass sharing the t_lds read and
// area_t (half LDS traffic, 2x VALU ILP). Ballot compaction, ascending-j
// order, transposed (e-major) storage. Arithmetic identical to reference.
// ---------------------------------------------------------------------------
__global__ __launch_bounds__(256) void cand_kernel(
    const float4* __restrict__ pred, const float4* __restrict__ tgt,
    int* __restrict__ counts, float2* __restrict__ cands)
{
    __shared__ float4 t_lds[NT];
    const int rb = blockIdx.x * 64;          // 64 rows per block, same image
    const int b  = rb >> 12;                 // NM = 4096
    for (int i = threadIdx.x; i < NT; i += 256)
        t_lds[i] = tgt[b * NT + i];
    __syncthreads();

    const int wv = threadIdx.x >> 6, lane = threadIdx.x & 63;
    const int row0 = rb + wv * 16;
    const unsigned long long lmask = (1ull << lane) - 1ull;

    float4 pa = pred[row0], pb = pred[row0 + 1];   // prefetch pair 0
    for (int rr = 0; rr < 16; rr += 2) {
        float4 p0 = pa, p1 = pb;
        if (rr + 2 < 16) {                         // prefetch next pair early
            pa = pred[row0 + rr + 2];
            pb = pred[row0 + rr + 3];
        }
        float ap0 = (p0.z - p0.x) * (p0.w - p0.y);
        float ap1 = (p1.z - p1.x) * (p1.w - p1.y);
        int base0 = 0, base1 = 0;
        #pragma unroll
        for (int pass = 0; pass < NT / 64; ++pass) {
            int j = (pass << 6) + lane;
            float4 t = t_lds[j];                   // shared by both rows
            float at = (t.z - t.x) * (t.w - t.y);  // shared
            float w0 = fmaxf(fminf(p0.z, t.z) - fmaxf(p0.x, t.x), 0.f);
            float h0 = fmaxf(fminf(p0.w, t.w) - fmaxf(p0.y, t.y), 0.f);
            float in0 = w0 * h0;
            float iou0 = in0 / ((ap0 + at) - in0); // ref association
            float w1 = fmaxf(fminf(p1.z, t.z) - fmaxf(p1.x, t.x), 0.f);
            float h1 = fmaxf(fminf(p1.w, t.w) - fmaxf(p1.y, t.y), 0.f);
            float in1 = w1 * h1;
            float iou1 = in1 / ((ap1 + at) - in1);
            bool q0 = iou0 > IOU_THR, q1 = iou1 > IOU_THR;
            unsigned long long m0 = __ballot(q0);
            unsigned long long m1 = __ballot(q1);
            if (q0) {
                int off = base0 + __popcll(m0 & lmask);
                if (off < CAP)
                    cands[(size_t)off * NROWS + row0 + rr] = make_float2(iou0, __int_as_float(j));
            }
            if (q1) {
                int off = base1 + __popcll(m1 & lmask);
                if (off < CAP)
                    cands[(size_t)off * NROWS + row0 + rr + 1] = make_float2(iou1, __int_as_float(j));
            }
            base0 += __popcll(m0);
            base1 += __popcll(m1);
        }
        if (lane == 0) {
            counts[row0 + rr]     = base0;         // > CAP flags overflow
            counts[row0 + rr + 1] = base1;
        }
    }
}

// ---------------------------------------------------------------------------
// Kernel 2: windowed auction (R10 protocol verbatim), 1024 threads/image,
// 1 row per thread per window, 4 ascending windows. Ascending windows
// resolved to their internal fixed point are FINAL (claim influence flows
// strictly upward in row index). Per round: recheck + register scan +
// atomicMin immediate-settle + ONE barrier (monotone lastprop stamp).
// All cross-wave correctness flows through barriers only (R11 lesson).
// claim[j] = min proposer (monotone) -> unique fixed point == serial greedy.
// ---------------------------------------------------------------------------
__global__ __launch_bounds__(T_WIN) void win_auction(
    const float4* __restrict__ pred, const float4* __restrict__ tgt,
    const int* __restrict__ counts, const float2* __restrict__ cands,
    float* __restrict__ per_img)
{
    __shared__ float4   t_lds[NT];       // 8 KB
    __shared__ unsigned claim[NT];       // 2 KB
    __shared__ int lastprop;             // monotone round stamp
    __shared__ unsigned char winovf[NWIN];
    __shared__ int ovf_min, ovf_res;
    __shared__ float rvv[T_WIN / 64];  __shared__ int rjj[T_WIN / 64];
    __shared__ float rls[T_WIN / 64];  __shared__ float rcs[T_WIN / 64];

    const int b = blockIdx.x, t = threadIdx.x, gbase = b * NM;
    const int wv = t >> 6, lane = t & 63;

    if (t < NT) {                        // T_WIN > NT: guard target-indexed init
        t_lds[t] = tgt[b * NT + t];
        claim[t] = SENT;
    }
    if (t < NWIN) winovf[t] = 0;
    if (t == 0) lastprop = -1;
    __syncthreads();

    // all counts up front (NWIN coalesced loads), flag overflow windows
    int allCnt[NWIN];
    #pragma unroll
    for (int k = 0; k < NWIN; ++k) {
        allCnt[k] = counts[gbase + k * T_WIN + t];
        if (allCnt[k] > CAP) winovf[k] = 1;
    }
    // prefetch window 0 candidates into registers
    float2 nC[CAP];
    #pragma unroll
    for (int e = 0; e < CAP; ++e) nC[e] = cands[(size_t)e * NROWS + gbase + t];
    __syncthreads();                      // winovf visible to all

    int rglob = 0;
    float2 cC[CAP];
    for (int w = 0; w < NWIN; ++w) {
        #pragma unroll
        for (int e = 0; e < CAP; ++e) cC[e] = nC[e];
        const int cCnt = allCnt[w];
        if (w + 1 < NWIN) {               // prefetch next window; hides under rounds
            #pragma unroll
            for (int e = 0; e < CAP; ++e)
                nC[e] = cands[(size_t)e * NROWS + gbase + (w + 1) * T_WIN + t];
        }
        const unsigned row = (unsigned)(w * T_WIN + t);
        int  stt  = (cCnt > 0 && cCnt <= CAP) ? 0 : 2;   // 0=UNRES 1=HOLD 2=DONE
        int  myj  = -1;
        bool isovf = (cCnt > CAP);
        int  ovfj  = -1;

        for (;;) {
            // ---- auction rounds to window fixed point (1 barrier/round) ----
            for (;;) {
                if (stt == 1 && claim[myj] != row) stt = 0;      // sniped: rejoin
                bool did = false;
                if (stt == 0) {
                    for (int it = 0; it <= CAP; ++it) {          // bounded retry
                        float bv = -1.f; int bj = -1;
                        #pragma unroll
                        for (int e = 0; e < CAP; ++e) {          // independent reads
                            float2 ce = cC[e];
                            int j = __float_as_int(ce.y) & (NT - 1);
                            unsigned cj = claim[j];
                            if (e < cCnt && cj >= row && ce.x > bv) { bv = ce.x; bj = j; }
                        }
                        if (bj < 0) { stt = 2; break; }          // invalid (permanent)
                        did = true;
                        unsigned old = atomicMin(&claim[bj], row);
                        if (old >= row) { myj = bj; stt = 1; break; }   // settled
                        // lost: claim[bj] < row is permanent -> excluded next scan
                    }
                }
                if (did) lastprop = rglob;    // benign: all writers store same value
                __syncthreads();
                int lp = lastprop;
                ++rglob;
                if (lp < rglob - 1) break;    // zero-proposal round: fixed point
            }
            // ---- overflow fallback (count > CAP, ~never) ----
            if (!winovf[w]) break;
            if (t == 0) ovf_min = 0x7FFFFFFF;
            __syncthreads();
            bool pend = isovf && (ovfj < 0 || claim[ovfj] != row);
            if (pend) atomicMin(&ovf_min, (int)row);
            __syncthreads();
            const int rowF = ovf_min;                            // uniform
            if (rowF == 0x7FFFFFFF) break;                       // window done
            {   // exact claim-aware argmax over all 512 targets (thread t = target t)
                float4 p4 = pred[gbase + rowF];                  // uniform address
                float v = -1.f; int bj = NT;
                if (t < NT) {
                    float4 tt = t_lds[t];
                    float area_p = (p4.z - p4.x) * (p4.w - p4.y);
                    float area_t = (tt.z - tt.x) * (tt.w - tt.y);
                    float wd = fmaxf(fminf(p4.z, tt.z) - fmaxf(p4.x, tt.x), 0.f);
                    float hd = fmaxf(fminf(p4.w, tt.w) - fmaxf(p4.y, tt.y), 0.f);
                    float inter = wd * hd;
                    float iou = inter / ((area_p + area_t) - inter);
                    bool freej = claim[t] > (unsigned)rowF;      // smaller = final-used
                    v = freej ? iou : -1.f;
                    bj = freej ? t : NT;
                }
                #pragma unroll
                for (int off = 1; off < 64; off <<= 1) {
                    float ov = __shfl_xor(v, off);
                    int   oj = __shfl_xor(bj, off);
                    if (ov > v || (ov == v && oj < bj)) { v = ov; bj = oj; }
                }
                if (lane == 0) { rvv[wv] = v; rjj[wv] = bj; }
            }
            __syncthreads();
            if (t == 0) {
                float v = rvv[0]; int bj = rjj[0];
                for (int q = 1; q < T_WIN / 64; ++q)
                    if (rvv[q] > v || (rvv[q] == v && rjj[q] < bj)) { v = rvv[q]; bj = rjj[q]; }
                if (v > IOU_THR) { ovf_res = bj; claim[bj] = (unsigned)rowF; }  // steal
                else ovf_res = -1;
            }
            __syncthreads();
            if ((int)row == rowF) {
                if (ovf_res >= 0) ovfj = ovf_res;   // matched (recorded in claim)
                else isovf = false;                 // permanently invalid
            }
            // displaced holder (if any) re-detected at next round's recheck
        }
    }
    __syncthreads();

    // ---- commit by target: claim[j]==r <=> r matched j (unique fixed point) ----
    float ls = 0.f, cs = 0.f;
    if (t < NT) {
        unsigned r = claim[t];
        if (r != SENT) {
            float4 p4 = pred[gbase + (int)r];
            float4 tt = t_lds[t];
            float inter = fmaxf(fminf(p4.z, tt.z) - fmaxf(p4.x, tt.x), 0.f) *
                          fmaxf(fminf(p4.w, tt.w) - fmaxf(p4.y, tt.y), 0.f);
            float area_p = (p4.z - p4.x) * (p4.w - p4.y);
            float area_t = (tt.z - tt.x) * (tt.w - tt.y);
            float uni = area_p + area_t - inter;
            float iou = inter / (uni + EPSG);
            float enc = (fmaxf(p4.z, tt.z) - fminf(p4.x, tt.x)) *
                        (fmaxf(p4.w, tt.w) - fminf(p4.y, tt.y));
            float giou = iou - (enc - uni) / (enc + EPSG);
            ls = 1.f - giou;
            cs = 1.f;
        }
    }
    #pragma unroll
    for (int off = 32; off >= 1; off >>= 1) {
        ls += __shfl_xor(ls, off);
        cs += __shfl_xor(cs, off);
    }
    if (lane == 0) { rls[wv] = ls; rcs[wv] = cs; }
    __syncthreads();
    if (t == 0) {
        float L = 0.f, C = 0.f;
        for (int q = 0; q < T_WIN / 64; ++q) { L += rls[q]; C += rcs[q]; }
        per_img[b] = (C > 0.f) ? L / C : 0.f;
    }
}

// ---------------------------------------------------------------------------
// Kernel 3: mean over images -> scalar output. Deterministic (no atomics).
// ---------------------------------------------------------------------------
__global__ void reduce_kernel(const float* __restrict__ per_img,
                              float* __restrict__ out)
{
    if (threadIdx.x == 0 && blockIdx.x == 0) {
        float s = 0.f;
        for (int i = 0; i < NB; ++i) s += per_img[i];
        out[0] = s / (float)NB;
    }
}

extern "C" void kernel_launch(void* const* d_in, const int* in_sizes, int n_in,
                              void* d_out, int out_size, void* d_ws, size_t ws_size,
                              hipStream_t stream)
{
    const float4* pred = (const float4*)d_in[0];   // [16,4096,4] f32
    const float4* tgt  = (const float4*)d_in[1];   // [16,512,4]  f32

    char* ws = (char*)d_ws;
    // layout: counts [NROWS] i32 | cands [CAP*NROWS] float2 | per_img [NB] f32
    int*    counts  = (int*)ws;
    size_t  off1    = (size_t)NROWS * sizeof(int);                 // 256 KB
    float2* cands   = (float2*)(ws + off1);
    size_t  off2    = off1 + (size_t)CAP * NROWS * sizeof(float2); // +8 MB
    float*  per_img = (float*)(ws + off2);

    cand_kernel<<<NROWS / 64, 256, 0, stream>>>(pred, tgt, counts, cands);
    win_auction<<<NB, T_WIN, 0, stream>>>(pred, tgt, counts, cands, per_img);
    reduce_kernel<<<1, 64, 0, stream>>>(per_img, (float*)d_out);
}